// Round 19
// baseline (341.840 us; speedup 1.0000x reference)
//
#include <hip/hip_runtime.h>

// Problem sizes (match reference)
#define NS0 300000
#define ND0 50000
#define NE0 800000
#define NS1 50000
#define ND1 8192
#define NE1 131072
#define IN_F 256
#define HID_F 128
#define SLOTS 64   // bucket-CSR capacity; indeg ~ Poisson(16), P(>=64) ~ 1e-19
#define NTILE (NS0 / 16)  // 18750 row-tiles for the dense GEMM
#define GRID 2048         // gemm+build kernel blocks (4 waves each)
#define TPLD 136          // tp row stride in halves (272B: 16B-aligned rows)

typedef __attribute__((ext_vector_type(8))) _Float16 half8_t;
typedef __attribute__((ext_vector_type(4))) _Float16 half4_t;
typedef __attribute__((ext_vector_type(4))) float f32x4;

// Workspace layout (4-byte words), all 16B-aligned:
#define OFF_OUTDEG0I 0
#define OFF_OUTDEG1I 300000
#define OFF_CNT0     350000
#define OFF_CNT1     400000
#define ZERO_WORDS   408192
#define OFF_EDGE0    408192
#define OFF_EDGE1    6808192
#define OFF_H1       7856768
#define OFF_W1X      14256768   // [128*256] fp16, fragment-dense repack
#define OFF_G        14273152   // [NS0*128] fp16

// ---------------- init: blocks [0,128) zero counters; [128,160) repack W1
// w1x fragment-dense layout: flat = (ct*8 + kb)*512 + (grp*16 + m)*8 + j
// holding W1[k = kb*32 + grp*8 + j][n = ct*16 + m]. Every B-frag load is a
// dense 1KB wave read (lane*16B), not 16 strided 64B segments.
__global__ __launch_bounds__(256) void k_init(
    int4* __restrict__ p, const float* __restrict__ W1,
    _Float16* __restrict__ w1x) {
  if (blockIdx.x < 128) {
    int i = blockIdx.x * 256 + threadIdx.x;
    for (; i < ZERO_WORDS / 4; i += 128 * 256) p[i] = make_int4(0, 0, 0, 0);
  } else {
    int f = (blockIdx.x - 128) * 256 + threadIdx.x;
    for (; f < IN_F * HID_F; f += 32 * 256) {
      const int ct = f >> 12;
      const int kb = (f >> 9) & 7;
      const int grpm = (f >> 3) & 63;
      const int j = f & 7;
      const int n = ct * 16 + (grpm & 15);
      const int k = kb * 32 + (grpm >> 4) * 8 + j;
      w1x[f] = (_Float16)W1[k * 128 + n];
    }
  }
}

// ---------------- wave-autonomous GEMM (ZERO barriers) + striped edge build.
// Each wave: (a) its stripe of the edge build (histogram + bucket scatter),
// (b) grid-strides over 16-row tiles: stage 16KB x densely -> wave-private
// LDS patch in fragment order (swizzle S = idx^kb^grp, proven r12) ->
// 64 MFMA (8 col-tiles, B from fragment-dense w1x, L1-hot 1KB loads) ->
// wave-private transpose patch -> 4 dense 1KB g-stores. Same-wave LDS ops
// process in order (r11-proven), so no syncthreads needed anywhere: no
// vmcnt drains, no cross-wave scheduling coupling, build truly overlaps.
__global__ __launch_bounds__(256) void k_gemm_wave(
    const float* __restrict__ x, const _Float16* __restrict__ w1x,
    _Float16* __restrict__ g,
    const int* __restrict__ src0, const int* __restrict__ dst0,
    const float* __restrict__ ew0, int* __restrict__ outdeg0,
    int* __restrict__ cnt0, int2* __restrict__ edge0,
    const int* __restrict__ src1, const int* __restrict__ dst1,
    const float* __restrict__ ew1, int* __restrict__ outdeg1,
    int* __restrict__ cnt1, int2* __restrict__ edge1) {
  __shared__ __align__(16) _Float16 patchA[4][16 * 256];  // 8KB per wave
  __shared__ __align__(16) _Float16 tpT[4][16 * TPLD];    // 4.25KB per wave
  const int tid = threadIdx.x;
  const int wv = tid >> 6;
  const int lane = tid & 63;
  const int grp = lane >> 4;
  const int m = lane & 15;
  const int skb = lane >> 3;          // staging: K-block
  const int sgrp = (lane >> 1) & 3;   // staging: k-octet group
  const int sjh = lane & 1;           // staging: octet half
  const int sidx_base = skb * 64 + sgrp * 16;
  const int sxor = skb ^ sgrp;

  // ---- (a) edge build stripe (no one in this kernel consumes it) ----
  {
    const int gl = blockIdx.x * 256 + tid;
    const int total = GRID * 256;
    for (int i = gl; i < NE0; i += total) {
      int s = src0[i];
      int d = dst0[i];
      float w = ew0[i];
      atomicAdd(&outdeg0[s], 1);
      int slot = atomicAdd(&cnt0[d], 1);
      if (slot < SLOTS) edge0[d * SLOTS + slot] = make_int2(s, __float_as_int(w));
    }
    for (int i = gl; i < NE1; i += total) {
      int s = src1[i];
      int d = dst1[i];
      float w = ew1[i];
      atomicAdd(&outdeg1[s], 1);
      int slot = atomicAdd(&cnt1[d], 1);
      if (slot < SLOTS) edge1[d * SLOTS + slot] = make_int2(s, __float_as_int(w));
    }
  }

  // ---- (b) wave-autonomous GEMM ----
  char* pa = reinterpret_cast<char*>(&patchA[wv][0]);
  _Float16* tp = &tpT[wv][0];
  const int gw = blockIdx.x * 4 + wv;

  for (int T = gw; T < NTILE; T += GRID * 4) {
    const float* xb = x + (size_t)T * 4096;
    // stage 16 rows: instr t = row t, dense 1KB (lane*16B); cvt; frag-order
#pragma unroll
    for (int t = 0; t < 16; ++t) {
      const float4 v = *reinterpret_cast<const float4*>(xb + t * 256 + lane * 4);
      half4_t h;
      h[0] = (_Float16)v.x; h[1] = (_Float16)v.y;
      h[2] = (_Float16)v.z; h[3] = (_Float16)v.w;
      const int S = (sidx_base + t) ^ sxor;
      *reinterpret_cast<half4_t*>(pa + S * 16 + sjh * 8) = h;
    }
    // 64 MFMA: A-frag from patch (proven mapping), B dense from w1x
    f32x4 acc[8];
#pragma unroll
    for (int ct = 0; ct < 8; ++ct) acc[ct] = (f32x4){0.f, 0.f, 0.f, 0.f};
#pragma unroll
    for (int kb = 0; kb < 8; ++kb) {
      const int Sr = (kb * 64 + lane) ^ kb ^ grp;
      const half8_t af = *reinterpret_cast<const half8_t*>(pa + Sr * 16);
#pragma unroll
      for (int ct = 0; ct < 8; ++ct) {
        const half8_t bf = *reinterpret_cast<const half8_t*>(
            w1x + (size_t)(ct * 8 + kb) * 512 + lane * 8);
        acc[ct] = __builtin_amdgcn_mfma_f32_16x16x32_f16(af, bf, acc[ct], 0, 0, 0);
      }
    }
    // epilogue: D (col = ct*16+m, row = 4*grp+r) -> tp row-major -> dense g
#pragma unroll
    for (int ct = 0; ct < 8; ++ct)
#pragma unroll
      for (int r = 0; r < 4; ++r)
        tp[(4 * grp + r) * TPLD + ct * 16 + m] = (_Float16)acc[ct][r];
#pragma unroll
    for (int q = 0; q < 4; ++q) {
      const int row = q * 4 + grp;
      const half8_t ov =
          *reinterpret_cast<const half8_t*>(tp + row * TPLD + m * 8);
      *reinterpret_cast<half8_t*>(
          g + ((size_t)T * 16 + row) * 128 + m * 8) = ov;
    }
  }
}

// ---------------- layer-1 aggregation over g (fp16, 77 MB, L3-resident):
// h1[d] = relu(rsqrt(indeg)*sum ew*rsqrt(outdeg0[src])*g[src] + b1) * rsqrt(outdeg1[d])
__global__ __launch_bounds__(256) void k_gather1(
    const _Float16* __restrict__ g, const int* __restrict__ cnt,
    const int2* __restrict__ edge, const int* __restrict__ outdeg0,
    const int* __restrict__ outdeg1, const float* __restrict__ b1,
    float* __restrict__ h1) {
  const int w = (blockIdx.x * 256 + threadIdx.x) >> 6;  // dst row
  const int lane = threadIdx.x & 63;
  const int gp = lane >> 4;
  const int sl = lane & 15;
  if (w >= ND0) return;
  const int deg = min(cnt[w], SLOTS);
  const int2* ep = edge + (size_t)w * SLOTS;
  float acc[8] = {0.f, 0.f, 0.f, 0.f, 0.f, 0.f, 0.f, 0.f};
  for (int e = 0; e < deg; e += 4) {
    const int idx = e + gp;
    int2 p = make_int2(0, 0);
    float c = 0.f;
    if (idx < deg) {
      p = ep[idx];
      c = __int_as_float(p.y) * rsqrtf(fmaxf((float)outdeg0[p.x], 1.0f));
    }
    const half8_t v =
        *reinterpret_cast<const half8_t*>(g + (size_t)p.x * 128 + sl * 8);
#pragma unroll
    for (int j = 0; j < 8; ++j) acc[j] = fmaf(c, (float)v[j], acc[j]);
  }
#pragma unroll
  for (int j = 0; j < 8; ++j) {
    acc[j] += __shfl_xor(acc[j], 16, 64);
    acc[j] += __shfl_xor(acc[j], 32, 64);
  }
  if (gp == 0) {
    const float sc = rsqrtf(fmaxf((float)deg, 1.0f));
    const float s1 = rsqrtf(fmaxf((float)outdeg1[w], 1.0f));
    const float4 bv0 = *reinterpret_cast<const float4*>(b1 + sl * 8);
    const float4 bv1 = *reinterpret_cast<const float4*>(b1 + sl * 8 + 4);
    float4 o0, o1;
    o0.x = fmaxf(fmaf(acc[0], sc, bv0.x), 0.0f) * s1;
    o0.y = fmaxf(fmaf(acc[1], sc, bv0.y), 0.0f) * s1;
    o0.z = fmaxf(fmaf(acc[2], sc, bv0.z), 0.0f) * s1;
    o0.w = fmaxf(fmaf(acc[3], sc, bv0.w), 0.0f) * s1;
    o1.x = fmaxf(fmaf(acc[4], sc, bv1.x), 0.0f) * s1;
    o1.y = fmaxf(fmaf(acc[5], sc, bv1.y), 0.0f) * s1;
    o1.z = fmaxf(fmaf(acc[6], sc, bv1.z), 0.0f) * s1;
    o1.w = fmaxf(fmaf(acc[7], sc, bv1.w), 0.0f) * s1;
    float* hr = h1 + (size_t)w * 128 + sl * 8;
    *reinterpret_cast<float4*>(hr) = o0;
    *reinterpret_cast<float4*>(hr + 4) = o1;
  }
}

#define FMA2(acc, c, v)        \
  acc.x = fmaf(c, v.x, acc.x); \
  acc.y = fmaf(c, v.y, acc.y);

// --------------------------------------------- fused gather + GEMM, layer 2
__global__ __launch_bounds__(256) void k_layer2(
    const float* __restrict__ h1, const int* __restrict__ cnt,
    const int2* __restrict__ edge, const float* __restrict__ W2,
    const float* __restrict__ b2, float* __restrict__ out) {
  __shared__ float arow[8][HID_F];
  const int t = blockIdx.x;
  const int wv = threadIdx.x >> 6;
  const int lane = threadIdx.x & 63;

#pragma unroll
  for (int rr = 0; rr < 2; ++rr) {
    const int row = t * 8 + wv * 2 + rr;
    const int deg = min(cnt[row], SLOTS);
    const int2* ep = edge + (size_t)row * SLOTS;
    float2 acc = make_float2(0.f, 0.f);
    int e = 0;
    for (; e + 4 <= deg; e += 4) {
      int4 q0 = *reinterpret_cast<const int4*>(ep + e);
      int4 q1 = *reinterpret_cast<const int4*>(ep + e + 2);
      float2 v0 = *reinterpret_cast<const float2*>(h1 + (size_t)q0.x * HID_F + lane * 2);
      float2 v1 = *reinterpret_cast<const float2*>(h1 + (size_t)q0.z * HID_F + lane * 2);
      float2 v2 = *reinterpret_cast<const float2*>(h1 + (size_t)q1.x * HID_F + lane * 2);
      float2 v3 = *reinterpret_cast<const float2*>(h1 + (size_t)q1.z * HID_F + lane * 2);
      FMA2(acc, __int_as_float(q0.y), v0);
      FMA2(acc, __int_as_float(q0.w), v1);
      FMA2(acc, __int_as_float(q1.y), v2);
      FMA2(acc, __int_as_float(q1.w), v3);
    }
    for (; e < deg; ++e) {
      int2 p = ep[e];
      float2 v = *reinterpret_cast<const float2*>(h1 + (size_t)p.x * HID_F + lane * 2);
      FMA2(acc, __int_as_float(p.y), v);
    }
    const float sc = rsqrtf(fmaxf((float)deg, 1.0f));
    *reinterpret_cast<float2*>(&arow[wv * 2 + rr][lane * 2]) =
        make_float2(acc.x * sc, acc.y * sc);
  }
  __syncthreads();

  const int j = threadIdx.x & 127;
  const int rg = threadIdx.x >> 7;
  float a0 = 0.f, a1 = 0.f, a2 = 0.f, a3 = 0.f;
  const float* wj = W2 + j;
#pragma unroll 8
  for (int k = 0; k < HID_F; ++k) {
    const float wvv = wj[(size_t)k * 128];
    a0 = fmaf(arow[rg * 4 + 0][k], wvv, a0);
    a1 = fmaf(arow[rg * 4 + 1][k], wvv, a1);
    a2 = fmaf(arow[rg * 4 + 2][k], wvv, a2);
    a3 = fmaf(arow[rg * 4 + 3][k], wvv, a3);
  }
  const float bj = b2[j];
  const int row0 = t * 8 + rg * 4;
  out[(size_t)(row0 + 0) * 128 + j] = fmaxf(a0 + bj, 0.0f);
  out[(size_t)(row0 + 1) * 128 + j] = fmaxf(a1 + bj, 0.0f);
  out[(size_t)(row0 + 2) * 128 + j] = fmaxf(a2 + bj, 0.0f);
  out[(size_t)(row0 + 3) * 128 + j] = fmaxf(a3 + bj, 0.0f);
}

extern "C" void kernel_launch(void* const* d_in, const int* in_sizes, int n_in,
                              void* d_out, int out_size, void* d_ws, size_t ws_size,
                              hipStream_t stream) {
  const float* x    = (const float*)d_in[0];
  const int*   src0 = (const int*)d_in[1];
  const int*   dst0 = (const int*)d_in[2];
  const float* ew0  = (const float*)d_in[3];
  const int*   src1 = (const int*)d_in[4];
  const int*   dst1 = (const int*)d_in[5];
  const float* ew1  = (const float*)d_in[6];
  const float* W1   = (const float*)d_in[7];
  const float* b1   = (const float*)d_in[8];
  const float* W2   = (const float*)d_in[9];
  const float* b2   = (const float*)d_in[10];
  float* out = (float*)d_out;

  int*   wsi = (int*)d_ws;
  float* wsf = (float*)d_ws;
  int* outdeg0 = wsi + OFF_OUTDEG0I;
  int* outdeg1 = wsi + OFF_OUTDEG1I;
  int* cnt0    = wsi + OFF_CNT0;
  int* cnt1    = wsi + OFF_CNT1;
  int2* edge0  = (int2*)(wsi + OFF_EDGE0);
  int2* edge1  = (int2*)(wsi + OFF_EDGE1);
  float* h1    = wsf + OFF_H1;
  _Float16* w1x = (_Float16*)(wsi + OFF_W1X);
  _Float16* g   = (_Float16*)(wsi + OFF_G);

  k_init<<<160, 256, 0, stream>>>((int4*)d_ws, W1, w1x);
  k_gemm_wave<<<GRID, 256, 0, stream>>>(
      x, w1x, g, src0, dst0, ew0, outdeg0, cnt0, edge0,
      src1, dst1, ew1, outdeg1, cnt1, edge1);
  k_gather1<<<(ND0 * 64) / 256, 256, 0, stream>>>(g, cnt0, edge0, outdeg0,
                                                  outdeg1, b1, h1);
  k_layer2<<<ND1 / 8, 256, 0, stream>>>(h1, cnt1, edge1, W2, b2, out);
}

// Round 20
// 228.053 us; speedup vs baseline: 1.4990x; 1.4990x over previous
//
#include <hip/hip_runtime.h>

// Problem sizes (match reference)
#define NS0 300000
#define ND0 50000
#define NE0 800000
#define NS1 50000
#define ND1 8192
#define NE1 131072
#define IN_F 256
#define HID_F 128
#define SLOTS 64    // bucket-CSR capacity; indeg ~ Poisson(16), P(>=64) ~ 1e-19
#define NT32 (NS0 / 32)  // 9375 32-row tiles for the dense GEMM
#define GEMM_GRID 2048
#define BUILD_GRID 512

typedef __attribute__((ext_vector_type(8))) _Float16 half8_t;
typedef __attribute__((ext_vector_type(4))) _Float16 half4_t;
typedef __attribute__((ext_vector_type(4))) float f32x4;

// Workspace layout (4-byte words), all 16B-aligned:
#define OFF_OUTDEG0I 0
#define OFF_OUTDEG1I 300000
#define OFF_CNT0     350000
#define OFF_CNT1     400000
#define ZERO_WORDS   408192
#define OFF_EDGE0    408192
#define OFF_EDGE1    6808192
#define OFF_H1       7856768
#define OFF_W1T      14256768
#define OFF_G        14273152

// ---------------- init: blocks [0,128) zero counters; [128,160) cvt W1->w1t
__global__ __launch_bounds__(256) void k_init(
    int4* __restrict__ p, const float* __restrict__ W1,
    _Float16* __restrict__ w1t) {
  if (blockIdx.x < 128) {
    int i = blockIdx.x * 256 + threadIdx.x;
    for (; i < ZERO_WORDS / 4; i += 128 * 256) p[i] = make_int4(0, 0, 0, 0);
  } else {
    int i = (blockIdx.x - 128) * 256 + threadIdx.x;
    for (; i < IN_F * HID_F; i += 32 * 256) {
      int k = i >> 7, n = i & 127;
      w1t[n * 256 + k] = (_Float16)W1[i];
    }
  }
}

// ---------------- fused: blocks [0, BUILD_GRID) edge build (first dispatch
// wave -> overlaps); blocks [BUILD_GRID, +GEMM_GRID) dense GEMM g = x@W1,
// 32-ROW tiles (r19 theory: fixed per-tile overhead ~5900cyc/CU against
// ~1700 useful; halve phases + double in-flight bytes per phase by doubling
// the tile). Same proven per-16-row fragment/swizzle staging, applied to
// each 16-row half; one __syncthreads per 32 rows.
#define LDB(p, o) (*reinterpret_cast<const half8_t*>((p) + (o)))
__global__ __launch_bounds__(256) void k_gemm_build(
    const float* __restrict__ x, const _Float16* __restrict__ w1t,
    _Float16* __restrict__ g,
    const int* __restrict__ src0, const int* __restrict__ dst0,
    const float* __restrict__ ew0, int* __restrict__ outdeg0,
    int* __restrict__ cnt0, int2* __restrict__ edge0,
    const int* __restrict__ src1, const int* __restrict__ dst1,
    const float* __restrict__ ew1, int* __restrict__ outdeg1,
    int* __restrict__ cnt1, int2* __restrict__ edge1) {
  __shared__ __align__(16) _Float16 ldsA[2][2][16 * 256];  // buf x half, 32KB
  __shared__ _Float16 ldsT[4][16 * 40];                     // wave transpose

  if (blockIdx.x < BUILD_GRID) {
    int tid = blockIdx.x * 256 + threadIdx.x;
    int stride = BUILD_GRID * 256;
    for (int i = tid; i < NE0; i += stride) {
      int s = src0[i];
      int d = dst0[i];
      float w = ew0[i];
      atomicAdd(&outdeg0[s], 1);
      int slot = atomicAdd(&cnt0[d], 1);
      if (slot < SLOTS) edge0[d * SLOTS + slot] = make_int2(s, __float_as_int(w));
    }
    for (int i = tid; i < NE1; i += stride) {
      int s = src1[i];
      int d = dst1[i];
      float w = ew1[i];
      atomicAdd(&outdeg1[s], 1);
      int slot = atomicAdd(&cnt1[d], 1);
      if (slot < SLOTS) edge1[d * SLOTS + slot] = make_int2(s, __float_as_int(w));
    }
    return;
  }

  // ---------------- GEMM path ----------------
  const int tid = threadIdx.x;
  const int wv = tid >> 6;
  const int lane = tid & 63;
  const int m = lane & 15;
  const int grp = lane >> 4;
  _Float16* tp = ldsT[wv];

  // B-frag: lane holds W1[k = kb*32 + grp*8 + j][n = 32wv + 16c + m]
  const _Float16* wb0 = w1t + (size_t)(32 * wv + m) * 256 + grp * 8;
  const _Float16* wb1 = wb0 + 16 * 256;
  const half8_t b00 = LDB(wb0, 0),   b01 = LDB(wb0, 32),  b02 = LDB(wb0, 64),
                b03 = LDB(wb0, 96),  b04 = LDB(wb0, 128), b05 = LDB(wb0, 160),
                b06 = LDB(wb0, 192), b07 = LDB(wb0, 224);
  const half8_t b10 = LDB(wb1, 0),   b11 = LDB(wb1, 32),  b12 = LDB(wb1, 64),
                b13 = LDB(wb1, 96),  b14 = LDB(wb1, 128), b15 = LDB(wb1, 160),
                b16 = LDB(wb1, 192), b17 = LDB(wb1, 224);

  // staging constants (swizzle S = idx ^ skb ^ sgrp; proven r12)
  const int skb = lane >> 3;
  const int sgrp = (lane >> 1) & 3;
  const int sjh = lane & 1;
  const int row_r = lane >> 2;   // epilogue: row 0..15 in half-tile
  const int q_r   = lane & 3;    // epilogue: 8-col quarter

  const int bid = blockIdx.x - BUILD_GRID;
  float4 pv[8];

#define LOAD_PV8(PV, T)                                                        \
  {                                                                            \
    const float* tb = x + (size_t)(T) * 8192;                                  \
    _Pragma("unroll") for (int r = 0; r < 8; ++r)                              \
        PV[r] = *reinterpret_cast<const float4*>(tb + tid * 4 + r * 1024);     \
  }

// row mr = wv + 4r (0..31); half h = mr>>4, local row lr = mr&15
#define WRITE_LDS32(BUFI, PV)                                                  \
  {                                                                            \
    char* Bp = reinterpret_cast<char*>(&ldsA[BUFI][0][0]);                     \
    _Pragma("unroll") for (int r = 0; r < 8; ++r) {                            \
      const int mr = wv + 4 * r;                                               \
      const int h = mr >> 4;                                                   \
      const int lr = mr & 15;                                                  \
      half4_t hv;                                                              \
      hv[0] = (_Float16)PV[r].x; hv[1] = (_Float16)PV[r].y;                    \
      hv[2] = (_Float16)PV[r].z; hv[3] = (_Float16)PV[r].w;                    \
      const int idx = skb * 64 + sgrp * 16 + lr;                               \
      const int S = idx ^ skb ^ sgrp;                                          \
      *reinterpret_cast<half4_t*>(Bp + h * 8192 + S * 16 + sjh * 8) = hv;      \
    }                                                                          \
  }

#define STEP(A, KB, B0, B1)                                                    \
  {                                                                            \
    const int Sr = ((KB * 64 + lane) ^ KB ^ grp);                              \
    const half8_t af = *reinterpret_cast<const half8_t*>(A + Sr * 16);         \
    acc0 = __builtin_amdgcn_mfma_f32_16x16x32_f16(af, B0, acc0, 0, 0, 0);      \
    acc1 = __builtin_amdgcn_mfma_f32_16x16x32_f16(af, B1, acc1, 0, 0, 0);      \
  }

// compute both 16-row halves of the 32-row tile; epilogue per half
#define COMPUTE32(BUFI, T)                                                     \
  _Pragma("unroll") for (int rt = 0; rt < 2; ++rt) {                           \
    const char* A = reinterpret_cast<const char*>(&ldsA[BUFI][rt][0]);         \
    f32x4 acc0 = {0.f, 0.f, 0.f, 0.f};                                         \
    f32x4 acc1 = {0.f, 0.f, 0.f, 0.f};                                         \
    STEP(A, 0, b00, b10) STEP(A, 1, b01, b11)                                  \
    STEP(A, 2, b02, b12) STEP(A, 3, b03, b13)                                  \
    STEP(A, 4, b04, b14) STEP(A, 5, b05, b15)                                  \
    STEP(A, 6, b06, b16) STEP(A, 7, b07, b17)                                  \
    _Pragma("unroll") for (int r = 0; r < 4; ++r) {                            \
      tp[(4 * grp + r) * 40 + m]      = (_Float16)acc0[r];                     \
      tp[(4 * grp + r) * 40 + 16 + m] = (_Float16)acc1[r];                     \
    }                                                                          \
    const half8_t ov =                                                         \
        *reinterpret_cast<const half8_t*>(tp + row_r * 40 + q_r * 8);          \
    *reinterpret_cast<half8_t*>(                                               \
        g + ((size_t)(T) * 32 + rt * 16 + row_r) * 128 + 32 * wv + q_r * 8) =  \
        ov;                                                                    \
  }

  // prologue: stage tile bid into buf 0 directly
  {
    const float* tb = x + (size_t)bid * 8192;
    char* Bp = reinterpret_cast<char*>(&ldsA[0][0][0]);
#pragma unroll
    for (int r = 0; r < 8; ++r) {
      const float4 v = *reinterpret_cast<const float4*>(tb + tid * 4 + r * 1024);
      const int mr = wv + 4 * r;
      const int h = mr >> 4;
      const int lr = mr & 15;
      half4_t hv;
      hv[0] = (_Float16)v.x; hv[1] = (_Float16)v.y;
      hv[2] = (_Float16)v.z; hv[3] = (_Float16)v.w;
      const int idx = skb * 64 + sgrp * 16 + lr;
      const int S = idx ^ skb ^ sgrp;
      *reinterpret_cast<half4_t*>(Bp + h * 8192 + S * 16 + sjh * 8) = hv;
    }
  }
  __syncthreads();

  int cur = 0;
  for (int t = bid; t < NT32; t += GEMM_GRID) {
    const int nxt = t + GEMM_GRID;
    if (nxt < NT32) LOAD_PV8(pv, nxt);   // issue next tile's loads
    COMPUTE32(cur, t);                    // 32 MFMA/wave from LDS
    if (nxt < NT32) WRITE_LDS32(cur ^ 1, pv);
    __syncthreads();                      // one barrier per 32 rows
    cur ^= 1;
  }
#undef LOAD_PV8
#undef WRITE_LDS32
#undef STEP
#undef COMPUTE32
}

// ---------------- layer-1 aggregation over g (fp16, 77 MB, L3-resident):
// h1[d] = relu(rsqrt(indeg)*sum ew*rsqrt(outdeg0[src])*g[src] + b1) * rsqrt(outdeg1[d])
__global__ __launch_bounds__(256) void k_gather1(
    const _Float16* __restrict__ g, const int* __restrict__ cnt,
    const int2* __restrict__ edge, const int* __restrict__ outdeg0,
    const int* __restrict__ outdeg1, const float* __restrict__ b1,
    float* __restrict__ h1) {
  const int w = (blockIdx.x * 256 + threadIdx.x) >> 6;  // dst row
  const int lane = threadIdx.x & 63;
  const int gp = lane >> 4;
  const int sl = lane & 15;
  if (w >= ND0) return;
  const int deg = min(cnt[w], SLOTS);
  const int2* ep = edge + (size_t)w * SLOTS;
  float acc[8] = {0.f, 0.f, 0.f, 0.f, 0.f, 0.f, 0.f, 0.f};
  for (int e = 0; e < deg; e += 4) {
    const int idx = e + gp;
    int2 p = make_int2(0, 0);
    float c = 0.f;
    if (idx < deg) {
      p = ep[idx];
      c = __int_as_float(p.y) * rsqrtf(fmaxf((float)outdeg0[p.x], 1.0f));
    }
    const half8_t v =
        *reinterpret_cast<const half8_t*>(g + (size_t)p.x * 128 + sl * 8);
#pragma unroll
    for (int j = 0; j < 8; ++j) acc[j] = fmaf(c, (float)v[j], acc[j]);
  }
#pragma unroll
  for (int j = 0; j < 8; ++j) {
    acc[j] += __shfl_xor(acc[j], 16, 64);
    acc[j] += __shfl_xor(acc[j], 32, 64);
  }
  if (gp == 0) {
    const float sc = rsqrtf(fmaxf((float)deg, 1.0f));
    const float s1 = rsqrtf(fmaxf((float)outdeg1[w], 1.0f));
    const float4 bv0 = *reinterpret_cast<const float4*>(b1 + sl * 8);
    const float4 bv1 = *reinterpret_cast<const float4*>(b1 + sl * 8 + 4);
    float4 o0, o1;
    o0.x = fmaxf(fmaf(acc[0], sc, bv0.x), 0.0f) * s1;
    o0.y = fmaxf(fmaf(acc[1], sc, bv0.y), 0.0f) * s1;
    o0.z = fmaxf(fmaf(acc[2], sc, bv0.z), 0.0f) * s1;
    o0.w = fmaxf(fmaf(acc[3], sc, bv0.w), 0.0f) * s1;
    o1.x = fmaxf(fmaf(acc[4], sc, bv1.x), 0.0f) * s1;
    o1.y = fmaxf(fmaf(acc[5], sc, bv1.y), 0.0f) * s1;
    o1.z = fmaxf(fmaf(acc[6], sc, bv1.z), 0.0f) * s1;
    o1.w = fmaxf(fmaf(acc[7], sc, bv1.w), 0.0f) * s1;
    float* hr = h1 + (size_t)w * 128 + sl * 8;
    *reinterpret_cast<float4*>(hr) = o0;
    *reinterpret_cast<float4*>(hr + 4) = o1;
  }
}

#define FMA2(acc, c, v)        \
  acc.x = fmaf(c, v.x, acc.x); \
  acc.y = fmaf(c, v.y, acc.y);

// --------------------------------------------- fused gather + GEMM, layer 2
__global__ __launch_bounds__(256) void k_layer2(
    const float* __restrict__ h1, const int* __restrict__ cnt,
    const int2* __restrict__ edge, const float* __restrict__ W2,
    const float* __restrict__ b2, float* __restrict__ out) {
  __shared__ float arow[8][HID_F];
  const int t = blockIdx.x;
  const int wv = threadIdx.x >> 6;
  const int lane = threadIdx.x & 63;

#pragma unroll
  for (int rr = 0; rr < 2; ++rr) {
    const int row = t * 8 + wv * 2 + rr;
    const int deg = min(cnt[row], SLOTS);
    const int2* ep = edge + (size_t)row * SLOTS;
    float2 acc = make_float2(0.f, 0.f);
    int e = 0;
    for (; e + 4 <= deg; e += 4) {
      int4 q0 = *reinterpret_cast<const int4*>(ep + e);
      int4 q1 = *reinterpret_cast<const int4*>(ep + e + 2);
      float2 v0 = *reinterpret_cast<const float2*>(h1 + (size_t)q0.x * HID_F + lane * 2);
      float2 v1 = *reinterpret_cast<const float2*>(h1 + (size_t)q0.z * HID_F + lane * 2);
      float2 v2 = *reinterpret_cast<const float2*>(h1 + (size_t)q1.x * HID_F + lane * 2);
      float2 v3 = *reinterpret_cast<const float2*>(h1 + (size_t)q1.z * HID_F + lane * 2);
      FMA2(acc, __int_as_float(q0.y), v0);
      FMA2(acc, __int_as_float(q0.w), v1);
      FMA2(acc, __int_as_float(q1.y), v2);
      FMA2(acc, __int_as_float(q1.w), v3);
    }
    for (; e < deg; ++e) {
      int2 p = ep[e];
      float2 v = *reinterpret_cast<const float2*>(h1 + (size_t)p.x * HID_F + lane * 2);
      FMA2(acc, __int_as_float(p.y), v);
    }
    const float sc = rsqrtf(fmaxf((float)deg, 1.0f));
    *reinterpret_cast<float2*>(&arow[wv * 2 + rr][lane * 2]) =
        make_float2(acc.x * sc, acc.y * sc);
  }
  __syncthreads();

  const int j = threadIdx.x & 127;
  const int rg = threadIdx.x >> 7;
  float a0 = 0.f, a1 = 0.f, a2 = 0.f, a3 = 0.f;
  const float* wj = W2 + j;
#pragma unroll 8
  for (int k = 0; k < HID_F; ++k) {
    const float wvv = wj[(size_t)k * 128];
    a0 = fmaf(arow[rg * 4 + 0][k], wvv, a0);
    a1 = fmaf(arow[rg * 4 + 1][k], wvv, a1);
    a2 = fmaf(arow[rg * 4 + 2][k], wvv, a2);
    a3 = fmaf(arow[rg * 4 + 3][k], wvv, a3);
  }
  const float bj = b2[j];
  const int row0 = t * 8 + rg * 4;
  out[(size_t)(row0 + 0) * 128 + j] = fmaxf(a0 + bj, 0.0f);
  out[(size_t)(row0 + 1) * 128 + j] = fmaxf(a1 + bj, 0.0f);
  out[(size_t)(row0 + 2) * 128 + j] = fmaxf(a2 + bj, 0.0f);
  out[(size_t)(row0 + 3) * 128 + j] = fmaxf(a3 + bj, 0.0f);
}

extern "C" void kernel_launch(void* const* d_in, const int* in_sizes, int n_in,
                              void* d_out, int out_size, void* d_ws, size_t ws_size,
                              hipStream_t stream) {
  const float* x    = (const float*)d_in[0];
  const int*   src0 = (const int*)d_in[1];
  const int*   dst0 = (const int*)d_in[2];
  const float* ew0  = (const float*)d_in[3];
  const int*   src1 = (const int*)d_in[4];
  const int*   dst1 = (const int*)d_in[5];
  const float* ew1  = (const float*)d_in[6];
  const float* W1   = (const float*)d_in[7];
  const float* b1   = (const float*)d_in[8];
  const float* W2   = (const float*)d_in[9];
  const float* b2   = (const float*)d_in[10];
  float* out = (float*)d_out;

  int*   wsi = (int*)d_ws;
  float* wsf = (float*)d_ws;
  int* outdeg0 = wsi + OFF_OUTDEG0I;
  int* outdeg1 = wsi + OFF_OUTDEG1I;
  int* cnt0    = wsi + OFF_CNT0;
  int* cnt1    = wsi + OFF_CNT1;
  int2* edge0  = (int2*)(wsi + OFF_EDGE0);
  int2* edge1  = (int2*)(wsi + OFF_EDGE1);
  float* h1    = wsf + OFF_H1;
  _Float16* w1t = (_Float16*)(wsi + OFF_W1T);
  _Float16* g   = (_Float16*)(wsi + OFF_G);

  k_init<<<160, 256, 0, stream>>>((int4*)d_ws, W1, w1t);
  k_gemm_build<<<GEMM_GRID + BUILD_GRID, 256, 0, stream>>>(
      x, w1t, g, src0, dst0, ew0, outdeg0, cnt0, edge0,
      src1, dst1, ew1, outdeg1, cnt1, edge1);
  k_gather1<<<(ND0 * 64) / 256, 256, 0, stream>>>(g, cnt0, edge0, outdeg0,
                                                  outdeg1, b1, h1);
  k_layer2<<<ND1 / 8, 256, 0, stream>>>(h1, cnt1, edge1, W2, b2, out);
}